// Round 12
// baseline (1351.531 us; speedup 1.0000x reference)
//
#include <hip/hip_runtime.h>

#define NN 2
#define CC 32
#define NCC 4
#define DD 96
#define WW 96
#define HH 96
#define PP (DD*WW*HH)          // 884736
#define NCP (NN*NCC*PP)        // 7077888
#define SD (WW*HH)             // 9216
#define SW HH                  // 96
#define EPS 1e-5f
#define HWP 100                // padded LDS row stride (floats)

#define CHUNK 2048                 // p per fused poolD+dots block (R7 optimum)
#define CHUNKS_PER_N (PP/CHUNK)    // 432

__device__ __forceinline__ float wave_reduce(float v) {
#pragma unroll
    for (int off = 32; off > 0; off >>= 1) v += __shfl_down(v, off, 64);
    return v;
}

__device__ __forceinline__ float dot4(float4 a, float4 b) {
    return a.x*b.x + a.y*b.y + a.z*b.z + a.w*b.w;
}

__device__ __forceinline__ float sigf(float v) { return 1.f / (1.f + __expf(-v)); }

__device__ __forceinline__ float4 sig4(float4 v) {
    return make_float4(sigf(v.x), sigf(v.y), sigf(v.z), sigf(v.w));
}

__device__ __forceinline__ float4 max4(float4 a, float4 b) {
    return make_float4(fmaxf(a.x,b.x), fmaxf(a.y,b.y), fmaxf(a.z,b.z), fmaxf(a.w,b.w));
}
__device__ __forceinline__ float4 min4(float4 a, float4 b) {
    return make_float4(fminf(a.x,b.x), fminf(a.y,b.y), fminf(a.z,b.z), fminf(a.w,b.w));
}

// ---- K1: fused H+W pools on RAW x (sigmoid deferred; monotone).
//      One (n,k,d) plane per block, staged in LDS. ----
__global__ __launch_bounds__(256) void k_poolHW(const float* __restrict__ x,
                                                float* __restrict__ omax,
                                                float* __restrict__ omin) {
    __shared__ float sx[96*HWP];     // raw plane
    __shared__ float smh[96*HWP];    // maxH plane
    int plane = blockIdx.x;          // (n*NCC+k)*DD + d
    const float* xp = x + (size_t)plane * SD;
    int t = threadIdx.x;

#pragma unroll
    for (int i = 0; i < 9; ++i) {
        int item = t + i*256;
        int w = item / 24, h0 = (item % 24)*4;
        *(float4*)(&sx[w*HWP + h0]) = *(const float4*)(xp + w*96 + h0);
    }
    __syncthreads();

    float4 rmn[9];
#pragma unroll
    for (int i = 0; i < 9; ++i) {
        int item = t + i*256;
        int w = item / 24, h0 = (item % 24)*4;
        const float* row = &sx[w*HWP];
        float v0 = row[h0], v1 = row[h0+1], v2 = row[h0+2], v3 = row[h0+3];
        float m2 = row[h0 > 2 ? h0-2 : 0];
        float m1 = row[h0 > 1 ? h0-1 : 0];
        float p4 = row[h0+4 < 96 ? h0+4 : 95];
        float p5 = row[h0+5 < 96 ? h0+5 : 95];
        float4 mx, mn;
        mx.x = fmaxf(fmaxf(m2,m1), fmaxf(fmaxf(v0,v1), v2));
        mx.y = fmaxf(m1, fmaxf(fmaxf(v0,v1), fmaxf(v2,v3)));
        mx.z = fmaxf(fmaxf(fmaxf(v0,v1), fmaxf(v2,v3)), p4);
        mx.w = fmaxf(fmaxf(v1,v2), fmaxf(v3, fmaxf(p4,p5)));
        mn.x = fminf(fminf(m2,m1), fminf(fminf(v0,v1), v2));
        mn.y = fminf(m1, fminf(fminf(v0,v1), fminf(v2,v3)));
        mn.z = fminf(fminf(fminf(v0,v1), fminf(v2,v3)), p4);
        mn.w = fminf(fminf(v1,v2), fminf(v3, fminf(p4,p5)));
        *(float4*)(&smh[w*HWP + h0]) = mx;
        rmn[i] = mn;
    }
    __syncthreads();

    float* oM = omax + (size_t)plane * SD;
    float* om = omin + (size_t)plane * SD;
#pragma unroll
    for (int i = 0; i < 9; ++i) {
        int item = t + i*256;
        int w = item / 24, h0 = (item % 24)*4;
        int w0 = (w > 2 ? w-2 : 0), w1 = (w > 1 ? w-1 : 0);
        int w3 = (w+1 < 96 ? w+1 : 95), w4 = (w+2 < 96 ? w+2 : 95);
        float4 a0 = *(const float4*)(&smh[w0*HWP + h0]);
        float4 a1 = *(const float4*)(&smh[w1*HWP + h0]);
        float4 a2 = *(const float4*)(&smh[w *HWP + h0]);
        float4 a3 = *(const float4*)(&smh[w3*HWP + h0]);
        float4 a4 = *(const float4*)(&smh[w4*HWP + h0]);
        float4 b0 = *(const float4*)(&sx[w0*HWP + h0]);
        float4 b1 = *(const float4*)(&sx[w1*HWP + h0]);
        float4 b2 = *(const float4*)(&sx[w *HWP + h0]);
        float4 b3 = *(const float4*)(&sx[w3*HWP + h0]);
        float4 b4 = *(const float4*)(&sx[w4*HWP + h0]);
        float4 MX = max4(max4(max4(a0,a1), max4(a2,a3)), a4);
        float4 MN = min4(min4(min4(b0,b1), min4(b2,b3)), min4(b4, rmn[i]));
        *(float4*)(oM + w*96 + h0) = MX;
        *(float4*)(om + w*96 + h0) = MN;
    }
}

// ---- K2: FUSED poolD + dots (CHUNK=2048, (512,4)) with phase-2 software
//      pipeline: iter-0 feat preloaded BEFORE the barrier; each iteration
//      issues iter+1's feat loads before consuming iter's. Forces the
//      allocator out of the spill-y 64-VGPR tier (R11: WRITE 27 MB). ----
__global__ __launch_bounds__(512, 4) void k_poolD_dots(const float* __restrict__ tmax,
                                                       const float* __restrict__ x,
                                                       const float* __restrict__ min12,
                                                       const float* __restrict__ feat,
                                                       float* __restrict__ dot_e,
                                                       float* __restrict__ dot_d,
                                                       float* __restrict__ fsum,
                                                       float* __restrict__ epart,
                                                       float* __restrict__ dpart) {
    __shared__ float es_s[NCC][CHUNK];   // 32 KB
    __shared__ float ds_s[NCC][CHUNK];   // 32 KB
    __shared__ float se[NCC], sdv[NCC];
    __shared__ float sacc[CC][9];

    int b = blockIdx.x;
    int n = b / CHUNKS_PER_N;
    int chunk = b % CHUNKS_PER_N;
    int pbase = chunk * CHUNK;
    int t = threadIdx.x;
    int wv = t >> 6, ln = t & 63;

    if (t < NCC) { se[t] = 0.f; sdv[t] = 0.f; }

    // ---------- phase 1: stencil + sigmoid -> LDS ----------
    {
        int il = t * 4;                       // 0..2047
        int p = pbase + il;
        int d = (p / SD) % DD;
        int o0 = ((d > 2 ? d - 2 : 0) - d) * SD;
        int o1 = ((d > 1 ? d - 1 : 0) - d) * SD;
        int o3 = ((d + 1 < DD ? d + 1 : DD - 1) - d) * SD;
        int o4 = ((d + 2 < DD ? d + 2 : DD - 1) - d) * SD;
        float ae[NCC], ad[NCC];
#pragma unroll
        for (int k = 0; k < NCC; ++k) {
            size_t i = (size_t)(n*NCC + k)*PP + p;
            const float* ta = tmax + i;
            const float* mm = x + i;
            float4 a0 = *(const float4*)(ta + o0);
            float4 a1 = *(const float4*)(ta + o1);
            float4 a2 = *(const float4*)(ta);
            float4 a3 = *(const float4*)(ta + o3);
            float4 a4 = *(const float4*)(ta + o4);
            float4 b0 = *(const float4*)(mm + o0);
            float4 b1 = *(const float4*)(mm + o1);
            float4 b2 = *(const float4*)(mm);
            float4 b3 = *(const float4*)(mm + o3);
            float4 b4 = *(const float4*)(mm + o4);
            float4 m12 = *(const float4*)(min12 + i);
            float4 mx = sig4(max4(max4(max4(a0, a1), max4(a2, a3)), a4));
            float4 ev = sig4(min4(m12, min4(min4(min4(b0, b1), min4(b2, b3)), b4)));
            *(float4*)(&ds_s[k][il]) = mx;
            *(float4*)(&es_s[k][il]) = ev;
            ae[k] = ev.x + ev.y + ev.z + ev.w;
            ad[k] = mx.x + mx.y + mx.z + mx.w;
        }
#pragma unroll
        for (int k = 0; k < NCC; ++k) {
            float re = wave_reduce(ae[k]);
            float rd = wave_reduce(ad[k]);
            if (ln == 0) { atomicAdd(&se[k], re); atomicAdd(&sdv[k], rd); }
        }
    }

    // ---------- phase 2 preload: iter-0 feat loads issued BEFORE barrier
    //            (independent of LDS; latency hides under barrier drain) ----
    int c0 = wv * 4;
    const float* fb = feat + ((size_t)n*CC + c0)*PP + pbase;
    int pl0 = ln*4;
    float4 nf0 = *(const float4*)(fb + 0*(size_t)PP + pl0);
    float4 nf1 = *(const float4*)(fb + 1*(size_t)PP + pl0);
    float4 nf2 = *(const float4*)(fb + 2*(size_t)PP + pl0);
    float4 nf3 = *(const float4*)(fb + 3*(size_t)PP + pl0);

    __syncthreads();
    if (t < NCC) {
        epart[(n*NCC + t)*CHUNKS_PER_N + chunk] = se[t];
        dpart[(n*NCC + t)*CHUNKS_PER_N + chunk] = sdv[t];
    }

    // ---------- phase 2: dots (8 waves x 4 channels), pipelined ----------
    float acc[4][9];
#pragma unroll
    for (int j = 0; j < 4; ++j)
#pragma unroll
        for (int q = 0; q < 9; ++q) acc[j][q] = 0.f;

    for (int it = 0; it < CHUNK/256; ++it) {     // 8 iters
        float4 f0 = nf0, f1 = nf1, f2 = nf2, f3 = nf3;
        if (it + 1 < CHUNK/256) {                // issue next-iter feat early
            int pn = (it+1)*256 + ln*4;
            nf0 = *(const float4*)(fb + 0*(size_t)PP + pn);
            nf1 = *(const float4*)(fb + 1*(size_t)PP + pn);
            nf2 = *(const float4*)(fb + 2*(size_t)PP + pn);
            nf3 = *(const float4*)(fb + 3*(size_t)PP + pn);
        }
        int pl = it*256 + ln*4;
        float4 e0 = *(const float4*)(&es_s[0][pl]);
        float4 e1 = *(const float4*)(&es_s[1][pl]);
        float4 e2 = *(const float4*)(&es_s[2][pl]);
        float4 e3 = *(const float4*)(&es_s[3][pl]);
        float4 d0 = *(const float4*)(&ds_s[0][pl]);
        float4 d1 = *(const float4*)(&ds_s[1][pl]);
        float4 d2 = *(const float4*)(&ds_s[2][pl]);
        float4 d3 = *(const float4*)(&ds_s[3][pl]);
#define ACCROW(j, f) \
        acc[j][0] += dot4(f, e0); acc[j][1] += dot4(f, e1); \
        acc[j][2] += dot4(f, e2); acc[j][3] += dot4(f, e3); \
        acc[j][4] += dot4(f, d0); acc[j][5] += dot4(f, d1); \
        acc[j][6] += dot4(f, d2); acc[j][7] += dot4(f, d3); \
        acc[j][8] += f.x + f.y + f.z + f.w;
        ACCROW(0, f0) ACCROW(1, f1) ACCROW(2, f2) ACCROW(3, f3)
#undef ACCROW
    }

#pragma unroll
    for (int j = 0; j < 4; ++j)
#pragma unroll
        for (int q = 0; q < 9; ++q) {
            float r = wave_reduce(acc[j][q]);
            if (ln == 0) sacc[c0 + j][q] = r;    // wave-disjoint rows
        }
    __syncthreads();
    if (t < CC*9) {
        int c = t / 9, q = t % 9;
        float v = sacc[c][q];
        if (q < 4)      atomicAdd(&dot_e[(n*CC + c)*NCC + q], v);
        else if (q < 8) atomicAdd(&dot_d[(n*CC + c)*NCC + (q - 4)], v);
        else            atomicAdd(&fsum[n*CC + c], v);
    }
}

// ---- K5: reduce esum/dsum partials, then cluster[n][k][c][{fore,back}] ----
__global__ __launch_bounds__(256) void k_cluster(const float* __restrict__ dot_e,
                                                 const float* __restrict__ dot_d,
                                                 const float* __restrict__ fsum,
                                                 const float* __restrict__ epart,
                                                 const float* __restrict__ dpart,
                                                 float* __restrict__ cluster) {
    __shared__ float es_s[NN*NCC], ds_s[NN*NCC];
    int t = threadIdx.x;              // 256 = N*NC*C
    {
        int nk = t >> 5, ln = t & 31;     // 8 groups x 32 lanes
        float pe = 0.f, pd = 0.f;
        for (int j = ln; j < CHUNKS_PER_N; j += 32) {
            pe += epart[nk*CHUNKS_PER_N + j];
            pd += dpart[nk*CHUNKS_PER_N + j];
        }
#pragma unroll
        for (int off = 16; off > 0; off >>= 1) {
            pe += __shfl_down(pe, off, 32);
            pd += __shfl_down(pd, off, 32);
        }
        if (ln == 0) { es_s[nk] = pe; ds_s[nk] = pd; }
    }
    __syncthreads();
    int n = t / (NCC*CC);
    int k = (t / CC) % NCC;
    int c = t % CC;
    float de = dot_e[(n*CC + c)*NCC + k];
    float dd = dot_d[(n*CC + c)*NCC + k];
    float fs = fsum[n*CC + c];
    float es = es_s[n*NCC + k] + EPS;
    float ds = ds_s[n*NCC + k] + EPS;
    float bs = (float)PP - ds_s[n*NCC + k] + EPS;
    float ec = de / es, dc = dd / ds, bc = (fs - dd) / bs;
    cluster[((n*NCC + k)*CC + c)*2 + 0] = ec + dc;
    cluster[((n*NCC + k)*CC + c)*2 + 1] = bc;
}

// ---- shared attn core: per-thread float4 of p, softmax weights s4[8]. ----
__device__ __forceinline__ void attn_weights(const float* __restrict__ fb,
                                             const float* __restrict__ cl,
                                             float4* s4) {
#pragma unroll
    for (int q = 0; q < 8; ++q) s4[q] = make_float4(0.f, 0.f, 0.f, 0.f);
#pragma unroll 8
    for (int c = 0; c < CC; ++c) {
        float4 f4 = *(const float4*)(fb + (size_t)c*PP);
#pragma unroll
        for (int k = 0; k < NCC; ++k) {
            float2 cv = *(const float2*)(cl + (k*CC + c)*2);
            s4[2*k].x   += f4.x*cv.x; s4[2*k].y   += f4.y*cv.x;
            s4[2*k].z   += f4.z*cv.x; s4[2*k].w   += f4.w*cv.x;
            s4[2*k+1].x += f4.x*cv.y; s4[2*k+1].y += f4.y*cv.y;
            s4[2*k+1].z += f4.z*cv.y; s4[2*k+1].w += f4.w*cv.y;
        }
    }
#pragma unroll
    for (int k = 0; k < NCC; ++k) {
        float4 a = s4[2*k], b = s4[2*k+1];
#define SMC(C) { float m = fmaxf(a.C, b.C); \
                 float e0 = __expf(a.C - m), e1 = __expf(b.C - m); \
                 float r = 1.f / (e0 + e1); \
                 s4[2*k].C = e0*r; s4[2*k+1].C = e1*r; }
        SMC(x) SMC(y) SMC(z) SMC(w)
#undef SMC
    }
}

// ---- K6a: attn + BN stats; persists 4 weights/p (w[2k+1] = 1-w[2k]). ----
__global__ __launch_bounds__(256, 4) void k_attn_stats(const float* __restrict__ feat,
                                                       const float* __restrict__ cluster,
                                                       const float* __restrict__ kptr,
                                                       float* __restrict__ wbuf,
                                                       float* __restrict__ bnsum,
                                                       float* __restrict__ bnsq) {
    __shared__ float cl[NCC*CC*2];        // 256
    __shared__ float sacc[CC][2];
    const int blocks_per_n = PP / 1024;   // 864
    int b = blockIdx.x;
    int n = b / blocks_per_n;
    int p0 = (b % blocks_per_n) * 1024 + threadIdx.x * 4;
    int t = threadIdx.x;

    cl[t] = cluster[n*NCC*CC*2 + t];
    if (t < CC*2) ((float*)sacc)[t] = 0.f;
    __syncthreads();

    const float* fb = feat + (size_t)n*CC*PP + p0;
    float4 s4[8];
    attn_weights(fb, cl, s4);
    float kk = kptr[0];

    // persist branch-0 weights: wbuf[(n*NCC + k)*PP + p]
    float* wb = wbuf + (size_t)n*NCC*PP + p0;
#pragma unroll
    for (int k = 0; k < NCC; ++k)
        *(float4*)(wb + (size_t)k*PP) = s4[2*k];

#pragma unroll 8
    for (int c = 0; c < CC; ++c) {
        float4 f4 = *(const float4*)(fb + (size_t)c*PP);   // L2-hot re-read
        float4 a4 = make_float4(0.f, 0.f, 0.f, 0.f);
#pragma unroll
        for (int k = 0; k < NCC; ++k) {
            float2 cv = *(const float2*)(cl + (k*CC + c)*2);
            a4.x += s4[2*k].x*cv.x + s4[2*k+1].x*cv.y;
            a4.y += s4[2*k].y*cv.x + s4[2*k+1].y*cv.y;
            a4.z += s4[2*k].z*cv.x + s4[2*k+1].z*cv.y;
            a4.w += s4[2*k].w*cv.x + s4[2*k+1].w*cv.y;
        }
        float ox = 5.f*f4.x + kk*a4.x;
        float oy = 5.f*f4.y + kk*a4.y;
        float oz = 5.f*f4.z + kk*a4.z;
        float ow = 5.f*f4.w + kk*a4.w;
        float so = ox + oy + oz + ow;
        float sq = ox*ox + oy*oy + oz*oz + ow*ow;
        so = wave_reduce(so); sq = wave_reduce(sq);
        if ((t & 63) == 0) { atomicAdd(&sacc[c][0], so); atomicAdd(&sacc[c][1], sq); }
    }
    __syncthreads();
    if (t < CC) {
        atomicAdd(&bnsum[t*16], sacc[t][0]);
        atomicAdd(&bnsq[t*16],  sacc[t][1]);
    }
}

// ---- K8: BN finalize (padded stats in) ----
__global__ __launch_bounds__(64) void k_bnfin(const float* __restrict__ bnsum,
                                              const float* __restrict__ bnsq,
                                              const float* __restrict__ wgt,
                                              const float* __restrict__ bias,
                                              float* __restrict__ scale,
                                              float* __restrict__ shift) {
    int c = threadIdx.x;
    if (c < CC) {
        float inv_n = 1.f / (float)((size_t)NN * PP);
        float mean = bnsum[c*16] * inv_n;
        float var  = bnsq[c*16] * inv_n - mean*mean;
        float inv  = 1.f / sqrtf(var + EPS);
        float sc = wgt[c] * inv;
        scale[c] = sc;
        shift[c] = bias[c] - mean*sc;
    }
}

// ---- K6b: load weights from wbuf, single feat pass, write normalized out. ----
__global__ __launch_bounds__(256, 4) void k_attn_write(const float* __restrict__ feat,
                                                       const float* __restrict__ cluster,
                                                       const float* __restrict__ wbuf,
                                                       const float* __restrict__ kptr,
                                                       const float* __restrict__ scale,
                                                       const float* __restrict__ shift,
                                                       float* __restrict__ out) {
    __shared__ float cl[NCC*CC*2];        // 256
    __shared__ float scl[CC], ssh[CC];
    const int blocks_per_n = PP / 1024;   // 864
    int b = blockIdx.x;
    int n = b / blocks_per_n;
    int p0 = (b % blocks_per_n) * 1024 + threadIdx.x * 4;
    int t = threadIdx.x;

    cl[t] = cluster[n*NCC*CC*2 + t];
    if (t < CC) { scl[t] = scale[t]; ssh[t] = shift[t]; }
    __syncthreads();

    const float* wb = wbuf + (size_t)n*NCC*PP + p0;
    float4 s4[8];
#pragma unroll
    for (int k = 0; k < NCC; ++k) {
        float4 w0 = *(const float4*)(wb + (size_t)k*PP);
        s4[2*k] = w0;
        s4[2*k+1] = make_float4(1.f - w0.x, 1.f - w0.y, 1.f - w0.z, 1.f - w0.w);
    }

    float kk = kptr[0];
    const float* fb = feat + (size_t)n*CC*PP + p0;
    float* ob = out + (size_t)n*CC*PP + p0;

#pragma unroll 8
    for (int c = 0; c < CC; ++c) {
        float4 f4 = *(const float4*)(fb + (size_t)c*PP);
        float4 a4 = make_float4(0.f, 0.f, 0.f, 0.f);
#pragma unroll
        for (int k = 0; k < NCC; ++k) {
            float2 cv = *(const float2*)(cl + (k*CC + c)*2);
            a4.x += s4[2*k].x*cv.x + s4[2*k+1].x*cv.y;
            a4.y += s4[2*k].y*cv.x + s4[2*k+1].y*cv.y;
            a4.z += s4[2*k].z*cv.x + s4[2*k+1].z*cv.y;
            a4.w += s4[2*k].w*cv.x + s4[2*k+1].w*cv.y;
        }
        float sc = scl[c], sh = ssh[c];
        float4 o;
        o.x = (5.f*f4.x + kk*a4.x)*sc + sh;
        o.y = (5.f*f4.y + kk*a4.y)*sc + sh;
        o.z = (5.f*f4.z + kk*a4.z)*sc + sh;
        o.w = (5.f*f4.w + kk*a4.w)*sc + sh;
        *(float4*)(ob + (size_t)c*PP) = o;
    }
}

extern "C" void kernel_launch(void* const* d_in, const int* in_sizes, int n_in,
                              void* d_out, int out_size, void* d_ws, size_t ws_size,
                              hipStream_t stream) {
    const float* feat = (const float*)d_in[0];
    const float* x    = (const float*)d_in[1];
    const float* kp   = (const float*)d_in[2];
    const float* bnw  = (const float*)d_in[3];
    const float* bnb  = (const float*)d_in[4];
    float* out = (float*)d_out;
    float* ws  = (float*)d_ws;

    float* wbuf = ws;                      // NCP (free region; 4 weights/p)
    float* t1   = ws + 2*(size_t)NCP;      // raw min(minH,minW)
    float* t2   = ws + 3*(size_t)NCP;      // raw maxW(maxH)
    float* acc  = ws + 6*(size_t)NCP;
    float* dot_e   = acc;          // 256
    float* dot_d   = acc + 256;    // 256
    float* fsum    = acc + 512;    // 64
    float* bnsum   = acc + 576;    // 512 (32 ch x 16 stride, padded)
    float* bnsq    = acc + 1088;   // 512 (padded)
    float* cluster = acc + 1600;   // 512
    float* scale   = acc + 2112;   // 32
    float* shift   = acc + 2144;   // 32
    float* epart   = acc + 2176;                          // 8*432 = 3456
    float* dpart   = acc + 2176 + NN*NCC*CHUNKS_PER_N;    // 3456

    hipMemsetAsync(acc, 0, 1600 * sizeof(float), stream);

    k_poolHW    <<<NN*NCC*DD, 256, 0, stream>>>(x, t2, t1);
    k_poolD_dots<<<NN*CHUNKS_PER_N, 512, 0, stream>>>(t2, x, t1, feat,
                                                      dot_e, dot_d, fsum, epart, dpart);
    k_cluster   <<<1, 256, 0, stream>>>(dot_e, dot_d, fsum, epart, dpart, cluster);
    k_attn_stats<<<NN*(PP/1024), 256, 0, stream>>>(feat, cluster, kp, wbuf, bnsum, bnsq);
    k_bnfin     <<<1, 64, 0, stream>>>(bnsum, bnsq, bnw, bnb, scale, shift);
    k_attn_write<<<NN*(PP/1024), 256, 0, stream>>>(feat, cluster, wbuf, kp, scale, shift, out);
}

// Round 14
// 622.893 us; speedup vs baseline: 2.1698x; 2.1698x over previous
//
#include <hip/hip_runtime.h>

#define NN 2
#define CC 32
#define NCC 4
#define DD 96
#define WW 96
#define HH 96
#define PP (DD*WW*HH)          // 884736
#define NCP (NN*NCC*PP)        // 7077888
#define SD (WW*HH)             // 9216
#define SW HH                  // 96
#define EPS 1e-5f
#define HWP 100                // padded LDS row stride (floats)

#define CHUNK 2048                 // p per fused poolD+dots block (R7 optimum)
#define CHUNKS_PER_N (PP/CHUNK)    // 432

typedef float f4nt __attribute__((ext_vector_type(4)));   // NT-store-compatible

__device__ __forceinline__ float wave_reduce(float v) {
#pragma unroll
    for (int off = 32; off > 0; off >>= 1) v += __shfl_down(v, off, 64);
    return v;
}

__device__ __forceinline__ float dot4(float4 a, float4 b) {
    return a.x*b.x + a.y*b.y + a.z*b.z + a.w*b.w;
}

__device__ __forceinline__ float sigf(float v) { return 1.f / (1.f + __expf(-v)); }

__device__ __forceinline__ float4 sig4(float4 v) {
    return make_float4(sigf(v.x), sigf(v.y), sigf(v.z), sigf(v.w));
}

__device__ __forceinline__ float4 max4(float4 a, float4 b) {
    return make_float4(fmaxf(a.x,b.x), fmaxf(a.y,b.y), fmaxf(a.z,b.z), fmaxf(a.w,b.w));
}
__device__ __forceinline__ float4 min4(float4 a, float4 b) {
    return make_float4(fminf(a.x,b.x), fminf(a.y,b.y), fminf(a.z,b.z), fminf(a.w,b.w));
}

// ---- K1: fused H+W pools on RAW x (sigmoid deferred; monotone).
//      One (n,k,d) plane per block, staged in LDS. ----
__global__ __launch_bounds__(256) void k_poolHW(const float* __restrict__ x,
                                                float* __restrict__ omax,
                                                float* __restrict__ omin) {
    __shared__ float sx[96*HWP];     // raw plane
    __shared__ float smh[96*HWP];    // maxH plane
    int plane = blockIdx.x;          // (n*NCC+k)*DD + d
    const float* xp = x + (size_t)plane * SD;
    int t = threadIdx.x;

#pragma unroll
    for (int i = 0; i < 9; ++i) {
        int item = t + i*256;
        int w = item / 24, h0 = (item % 24)*4;
        *(float4*)(&sx[w*HWP + h0]) = *(const float4*)(xp + w*96 + h0);
    }
    __syncthreads();

    float4 rmn[9];
#pragma unroll
    for (int i = 0; i < 9; ++i) {
        int item = t + i*256;
        int w = item / 24, h0 = (item % 24)*4;
        const float* row = &sx[w*HWP];
        float v0 = row[h0], v1 = row[h0+1], v2 = row[h0+2], v3 = row[h0+3];
        float m2 = row[h0 > 2 ? h0-2 : 0];
        float m1 = row[h0 > 1 ? h0-1 : 0];
        float p4 = row[h0+4 < 96 ? h0+4 : 95];
        float p5 = row[h0+5 < 96 ? h0+5 : 95];
        float4 mx, mn;
        mx.x = fmaxf(fmaxf(m2,m1), fmaxf(fmaxf(v0,v1), v2));
        mx.y = fmaxf(m1, fmaxf(fmaxf(v0,v1), fmaxf(v2,v3)));
        mx.z = fmaxf(fmaxf(fmaxf(v0,v1), fmaxf(v2,v3)), p4);
        mx.w = fmaxf(fmaxf(v1,v2), fmaxf(v3, fmaxf(p4,p5)));
        mn.x = fminf(fminf(m2,m1), fminf(fminf(v0,v1), v2));
        mn.y = fminf(m1, fminf(fminf(v0,v1), fminf(v2,v3)));
        mn.z = fminf(fminf(fminf(v0,v1), fminf(v2,v3)), p4);
        mn.w = fminf(fminf(v1,v2), fminf(v3, fminf(p4,p5)));
        *(float4*)(&smh[w*HWP + h0]) = mx;
        rmn[i] = mn;
    }
    __syncthreads();

    float* oM = omax + (size_t)plane * SD;
    float* om = omin + (size_t)plane * SD;
#pragma unroll
    for (int i = 0; i < 9; ++i) {
        int item = t + i*256;
        int w = item / 24, h0 = (item % 24)*4;
        int w0 = (w > 2 ? w-2 : 0), w1 = (w > 1 ? w-1 : 0);
        int w3 = (w+1 < 96 ? w+1 : 95), w4 = (w+2 < 96 ? w+2 : 95);
        float4 a0 = *(const float4*)(&smh[w0*HWP + h0]);
        float4 a1 = *(const float4*)(&smh[w1*HWP + h0]);
        float4 a2 = *(const float4*)(&smh[w *HWP + h0]);
        float4 a3 = *(const float4*)(&smh[w3*HWP + h0]);
        float4 a4 = *(const float4*)(&smh[w4*HWP + h0]);
        float4 b0 = *(const float4*)(&sx[w0*HWP + h0]);
        float4 b1 = *(const float4*)(&sx[w1*HWP + h0]);
        float4 b2 = *(const float4*)(&sx[w *HWP + h0]);
        float4 b3 = *(const float4*)(&sx[w3*HWP + h0]);
        float4 b4 = *(const float4*)(&sx[w4*HWP + h0]);
        float4 MX = max4(max4(max4(a0,a1), max4(a2,a3)), a4);
        float4 MN = min4(min4(min4(b0,b1), min4(b2,b3)), min4(b4, rmn[i]));
        *(float4*)(oM + w*96 + h0) = MX;
        *(float4*)(om + w*96 + h0) = MN;
    }
}

// ---- K2: FUSED poolD + dots (EXACT R7/R11 form: CHUNK=2048, no pragmas,
//      no pipeline, (512,4)). Verified 148-149 us / WRITE 27 MB twice.
//      R8/R9/R12 lesson: ANY restructure of phase 2 (bound tier, unroll,
//      manual pipeline) triggers allocator spill (up to 1.2 GB scratch).
//      Do not touch this kernel. ----
__global__ __launch_bounds__(512, 4) void k_poolD_dots(const float* __restrict__ tmax,
                                                       const float* __restrict__ x,
                                                       const float* __restrict__ min12,
                                                       const float* __restrict__ feat,
                                                       float* __restrict__ dot_e,
                                                       float* __restrict__ dot_d,
                                                       float* __restrict__ fsum,
                                                       float* __restrict__ epart,
                                                       float* __restrict__ dpart) {
    __shared__ float es_s[NCC][CHUNK];   // 32 KB
    __shared__ float ds_s[NCC][CHUNK];   // 32 KB
    __shared__ float se[NCC], sdv[NCC];
    __shared__ float sacc[CC][9];

    int b = blockIdx.x;
    int n = b / CHUNKS_PER_N;
    int chunk = b % CHUNKS_PER_N;
    int pbase = chunk * CHUNK;
    int t = threadIdx.x;
    int wv = t >> 6, ln = t & 63;

    if (t < NCC) { se[t] = 0.f; sdv[t] = 0.f; }

    // ---------- phase 1: stencil + sigmoid -> LDS ----------
    {
        int il = t * 4;                       // 0..2047
        int p = pbase + il;
        int d = (p / SD) % DD;
        int o0 = ((d > 2 ? d - 2 : 0) - d) * SD;
        int o1 = ((d > 1 ? d - 1 : 0) - d) * SD;
        int o3 = ((d + 1 < DD ? d + 1 : DD - 1) - d) * SD;
        int o4 = ((d + 2 < DD ? d + 2 : DD - 1) - d) * SD;
        float ae[NCC], ad[NCC];
#pragma unroll
        for (int k = 0; k < NCC; ++k) {
            size_t i = (size_t)(n*NCC + k)*PP + p;
            const float* ta = tmax + i;
            const float* mm = x + i;
            float4 a0 = *(const float4*)(ta + o0);
            float4 a1 = *(const float4*)(ta + o1);
            float4 a2 = *(const float4*)(ta);
            float4 a3 = *(const float4*)(ta + o3);
            float4 a4 = *(const float4*)(ta + o4);
            float4 b0 = *(const float4*)(mm + o0);
            float4 b1 = *(const float4*)(mm + o1);
            float4 b2 = *(const float4*)(mm);
            float4 b3 = *(const float4*)(mm + o3);
            float4 b4 = *(const float4*)(mm + o4);
            float4 m12 = *(const float4*)(min12 + i);
            float4 mx = sig4(max4(max4(max4(a0, a1), max4(a2, a3)), a4));
            float4 ev = sig4(min4(m12, min4(min4(min4(b0, b1), min4(b2, b3)), b4)));
            *(float4*)(&ds_s[k][il]) = mx;
            *(float4*)(&es_s[k][il]) = ev;
            ae[k] = ev.x + ev.y + ev.z + ev.w;
            ad[k] = mx.x + mx.y + mx.z + mx.w;
        }
#pragma unroll
        for (int k = 0; k < NCC; ++k) {
            float re = wave_reduce(ae[k]);
            float rd = wave_reduce(ad[k]);
            if (ln == 0) { atomicAdd(&se[k], re); atomicAdd(&sdv[k], rd); }
        }
    }
    __syncthreads();
    if (t < NCC) {
        epart[(n*NCC + t)*CHUNKS_PER_N + chunk] = se[t];
        dpart[(n*NCC + t)*CHUNKS_PER_N + chunk] = sdv[t];
    }

    // ---------- phase 2: dots (8 waves x 4 channels) ----------
    int c0 = wv * 4;
    const float* fb = feat + ((size_t)n*CC + c0)*PP + pbase;

    float acc[4][9];
#pragma unroll
    for (int j = 0; j < 4; ++j)
#pragma unroll
        for (int q = 0; q < 9; ++q) acc[j][q] = 0.f;

    for (int it = 0; it < CHUNK/256; ++it) {     // 8 iters
        int pl = it*256 + ln*4;
        float4 f0 = *(const float4*)(fb + 0*(size_t)PP + pl);
        float4 f1 = *(const float4*)(fb + 1*(size_t)PP + pl);
        float4 f2 = *(const float4*)(fb + 2*(size_t)PP + pl);
        float4 f3 = *(const float4*)(fb + 3*(size_t)PP + pl);
        float4 e0 = *(const float4*)(&es_s[0][pl]);
        float4 e1 = *(const float4*)(&es_s[1][pl]);
        float4 e2 = *(const float4*)(&es_s[2][pl]);
        float4 e3 = *(const float4*)(&es_s[3][pl]);
        float4 d0 = *(const float4*)(&ds_s[0][pl]);
        float4 d1 = *(const float4*)(&ds_s[1][pl]);
        float4 d2 = *(const float4*)(&ds_s[2][pl]);
        float4 d3 = *(const float4*)(&ds_s[3][pl]);
#define ACCROW(j, f) \
        acc[j][0] += dot4(f, e0); acc[j][1] += dot4(f, e1); \
        acc[j][2] += dot4(f, e2); acc[j][3] += dot4(f, e3); \
        acc[j][4] += dot4(f, d0); acc[j][5] += dot4(f, d1); \
        acc[j][6] += dot4(f, d2); acc[j][7] += dot4(f, d3); \
        acc[j][8] += f.x + f.y + f.z + f.w;
        ACCROW(0, f0) ACCROW(1, f1) ACCROW(2, f2) ACCROW(3, f3)
#undef ACCROW
    }

#pragma unroll
    for (int j = 0; j < 4; ++j)
#pragma unroll
        for (int q = 0; q < 9; ++q) {
            float r = wave_reduce(acc[j][q]);
            if (ln == 0) sacc[c0 + j][q] = r;    // wave-disjoint rows
        }
    __syncthreads();
    if (t < CC*9) {
        int c = t / 9, q = t % 9;
        float v = sacc[c][q];
        if (q < 4)      atomicAdd(&dot_e[(n*CC + c)*NCC + q], v);
        else if (q < 8) atomicAdd(&dot_d[(n*CC + c)*NCC + (q - 4)], v);
        else            atomicAdd(&fsum[n*CC + c], v);
    }
}

// ---- K5: reduce esum/dsum partials, then cluster[n][k][c][{fore,back}] ----
__global__ __launch_bounds__(256) void k_cluster(const float* __restrict__ dot_e,
                                                 const float* __restrict__ dot_d,
                                                 const float* __restrict__ fsum,
                                                 const float* __restrict__ epart,
                                                 const float* __restrict__ dpart,
                                                 float* __restrict__ cluster) {
    __shared__ float es_s[NN*NCC], ds_s[NN*NCC];
    int t = threadIdx.x;              // 256 = N*NC*C
    {
        int nk = t >> 5, ln = t & 31;     // 8 groups x 32 lanes
        float pe = 0.f, pd = 0.f;
        for (int j = ln; j < CHUNKS_PER_N; j += 32) {
            pe += epart[nk*CHUNKS_PER_N + j];
            pd += dpart[nk*CHUNKS_PER_N + j];
        }
#pragma unroll
        for (int off = 16; off > 0; off >>= 1) {
            pe += __shfl_down(pe, off, 32);
            pd += __shfl_down(pd, off, 32);
        }
        if (ln == 0) { es_s[nk] = pe; ds_s[nk] = pd; }
    }
    __syncthreads();
    int n = t / (NCC*CC);
    int k = (t / CC) % NCC;
    int c = t % CC;
    float de = dot_e[(n*CC + c)*NCC + k];
    float dd = dot_d[(n*CC + c)*NCC + k];
    float fs = fsum[n*CC + c];
    float es = es_s[n*NCC + k] + EPS;
    float ds = ds_s[n*NCC + k] + EPS;
    float bs = (float)PP - ds_s[n*NCC + k] + EPS;
    float ec = de / es, dc = dd / ds, bc = (fs - dd) / bs;
    cluster[((n*NCC + k)*CC + c)*2 + 0] = ec + dc;
    cluster[((n*NCC + k)*CC + c)*2 + 1] = bc;
}

// ---- shared attn core: per-thread float4 of p, softmax weights s4[8]. ----
__device__ __forceinline__ void attn_weights(const float* __restrict__ fb,
                                             const float* __restrict__ cl,
                                             float4* s4) {
#pragma unroll
    for (int q = 0; q < 8; ++q) s4[q] = make_float4(0.f, 0.f, 0.f, 0.f);
#pragma unroll 8
    for (int c = 0; c < CC; ++c) {
        float4 f4 = *(const float4*)(fb + (size_t)c*PP);
#pragma unroll
        for (int k = 0; k < NCC; ++k) {
            float2 cv = *(const float2*)(cl + (k*CC + c)*2);
            s4[2*k].x   += f4.x*cv.x; s4[2*k].y   += f4.y*cv.x;
            s4[2*k].z   += f4.z*cv.x; s4[2*k].w   += f4.w*cv.x;
            s4[2*k+1].x += f4.x*cv.y; s4[2*k+1].y += f4.y*cv.y;
            s4[2*k+1].z += f4.z*cv.y; s4[2*k+1].w += f4.w*cv.y;
        }
    }
#pragma unroll
    for (int k = 0; k < NCC; ++k) {
        float4 a = s4[2*k], b = s4[2*k+1];
#define SMC(C) { float m = fmaxf(a.C, b.C); \
                 float e0 = __expf(a.C - m), e1 = __expf(b.C - m); \
                 float r = 1.f / (e0 + e1); \
                 s4[2*k].C = e0*r; s4[2*k+1].C = e1*r; }
        SMC(x) SMC(y) SMC(z) SMC(w)
#undef SMC
    }
}

// ---- K6a: attn + BN stats; persists 4 weights/p (w[2k+1] = 1-w[2k]). ----
__global__ __launch_bounds__(256, 4) void k_attn_stats(const float* __restrict__ feat,
                                                       const float* __restrict__ cluster,
                                                       const float* __restrict__ kptr,
                                                       float* __restrict__ wbuf,
                                                       float* __restrict__ bnsum,
                                                       float* __restrict__ bnsq) {
    __shared__ float cl[NCC*CC*2];        // 256
    __shared__ float sacc[CC][2];
    const int blocks_per_n = PP / 1024;   // 864
    int b = blockIdx.x;
    int n = b / blocks_per_n;
    int p0 = (b % blocks_per_n) * 1024 + threadIdx.x * 4;
    int t = threadIdx.x;

    cl[t] = cluster[n*NCC*CC*2 + t];
    if (t < CC*2) ((float*)sacc)[t] = 0.f;
    __syncthreads();

    const float* fb = feat + (size_t)n*CC*PP + p0;
    float4 s4[8];
    attn_weights(fb, cl, s4);
    float kk = kptr[0];

    // persist branch-0 weights: wbuf[(n*NCC + k)*PP + p]
    float* wb = wbuf + (size_t)n*NCC*PP + p0;
#pragma unroll
    for (int k = 0; k < NCC; ++k)
        *(float4*)(wb + (size_t)k*PP) = s4[2*k];

#pragma unroll 8
    for (int c = 0; c < CC; ++c) {
        float4 f4 = *(const float4*)(fb + (size_t)c*PP);   // L2-hot re-read
        float4 a4 = make_float4(0.f, 0.f, 0.f, 0.f);
#pragma unroll
        for (int k = 0; k < NCC; ++k) {
            float2 cv = *(const float2*)(cl + (k*CC + c)*2);
            a4.x += s4[2*k].x*cv.x + s4[2*k+1].x*cv.y;
            a4.y += s4[2*k].y*cv.x + s4[2*k+1].y*cv.y;
            a4.z += s4[2*k].z*cv.x + s4[2*k+1].z*cv.y;
            a4.w += s4[2*k].w*cv.x + s4[2*k+1].w*cv.y;
        }
        float ox = 5.f*f4.x + kk*a4.x;
        float oy = 5.f*f4.y + kk*a4.y;
        float oz = 5.f*f4.z + kk*a4.z;
        float ow = 5.f*f4.w + kk*a4.w;
        float so = ox + oy + oz + ow;
        float sq = ox*ox + oy*oy + oz*oz + ow*ow;
        so = wave_reduce(so); sq = wave_reduce(sq);
        if ((t & 63) == 0) { atomicAdd(&sacc[c][0], so); atomicAdd(&sacc[c][1], sq); }
    }
    __syncthreads();
    if (t < CC) {
        atomicAdd(&bnsum[t*16], sacc[t][0]);
        atomicAdd(&bnsq[t*16],  sacc[t][1]);
    }
}

// ---- K8: BN finalize (padded stats in) ----
__global__ __launch_bounds__(64) void k_bnfin(const float* __restrict__ bnsum,
                                              const float* __restrict__ bnsq,
                                              const float* __restrict__ wgt,
                                              const float* __restrict__ bias,
                                              float* __restrict__ scale,
                                              float* __restrict__ shift) {
    int c = threadIdx.x;
    if (c < CC) {
        float inv_n = 1.f / (float)((size_t)NN * PP);
        float mean = bnsum[c*16] * inv_n;
        float var  = bnsq[c*16] * inv_n - mean*mean;
        float inv  = 1.f / sqrtf(var + EPS);
        float sc = wgt[c] * inv;
        scale[c] = sc;
        shift[c] = bias[c] - mean*sc;
    }
}

// ---- K6b: load weights from wbuf, single feat pass, write normalized out.
//      out stores are NON-TEMPORAL (via clang ext-vector alias): out is never
//      re-read, so bypass L2 and keep it free for the feat read stream. ----
__global__ __launch_bounds__(256, 4) void k_attn_write(const float* __restrict__ feat,
                                                       const float* __restrict__ cluster,
                                                       const float* __restrict__ wbuf,
                                                       const float* __restrict__ kptr,
                                                       const float* __restrict__ scale,
                                                       const float* __restrict__ shift,
                                                       float* __restrict__ out) {
    __shared__ float cl[NCC*CC*2];        // 256
    __shared__ float scl[CC], ssh[CC];
    const int blocks_per_n = PP / 1024;   // 864
    int b = blockIdx.x;
    int n = b / blocks_per_n;
    int p0 = (b % blocks_per_n) * 1024 + threadIdx.x * 4;
    int t = threadIdx.x;

    cl[t] = cluster[n*NCC*CC*2 + t];
    if (t < CC) { scl[t] = scale[t]; ssh[t] = shift[t]; }
    __syncthreads();

    const float* wb = wbuf + (size_t)n*NCC*PP + p0;
    float4 s4[8];
#pragma unroll
    for (int k = 0; k < NCC; ++k) {
        float4 w0 = *(const float4*)(wb + (size_t)k*PP);
        s4[2*k] = w0;
        s4[2*k+1] = make_float4(1.f - w0.x, 1.f - w0.y, 1.f - w0.z, 1.f - w0.w);
    }

    float kk = kptr[0];
    const float* fb = feat + (size_t)n*CC*PP + p0;
    float* ob = out + (size_t)n*CC*PP + p0;

#pragma unroll 8
    for (int c = 0; c < CC; ++c) {
        float4 f4 = *(const float4*)(fb + (size_t)c*PP);
        float4 a4 = make_float4(0.f, 0.f, 0.f, 0.f);
#pragma unroll
        for (int k = 0; k < NCC; ++k) {
            float2 cv = *(const float2*)(cl + (k*CC + c)*2);
            a4.x += s4[2*k].x*cv.x + s4[2*k+1].x*cv.y;
            a4.y += s4[2*k].y*cv.x + s4[2*k+1].y*cv.y;
            a4.z += s4[2*k].z*cv.x + s4[2*k+1].z*cv.y;
            a4.w += s4[2*k].w*cv.x + s4[2*k+1].w*cv.y;
        }
        float sc = scl[c], sh = ssh[c];
        f4nt o;
        o.x = (5.f*f4.x + kk*a4.x)*sc + sh;
        o.y = (5.f*f4.y + kk*a4.y)*sc + sh;
        o.z = (5.f*f4.z + kk*a4.z)*sc + sh;
        o.w = (5.f*f4.w + kk*a4.w)*sc + sh;
        __builtin_nontemporal_store(o, (f4nt*)(ob + (size_t)c*PP));
    }
}

extern "C" void kernel_launch(void* const* d_in, const int* in_sizes, int n_in,
                              void* d_out, int out_size, void* d_ws, size_t ws_size,
                              hipStream_t stream) {
    const float* feat = (const float*)d_in[0];
    const float* x    = (const float*)d_in[1];
    const float* kp   = (const float*)d_in[2];
    const float* bnw  = (const float*)d_in[3];
    const float* bnb  = (const float*)d_in[4];
    float* out = (float*)d_out;
    float* ws  = (float*)d_ws;

    float* wbuf = ws;                      // NCP (free region; 4 weights/p)
    float* t1   = ws + 2*(size_t)NCP;      // raw min(minH,minW)
    float* t2   = ws + 3*(size_t)NCP;      // raw maxW(maxH)
    float* acc  = ws + 6*(size_t)NCP;
    float* dot_e   = acc;          // 256
    float* dot_d   = acc + 256;    // 256
    float* fsum    = acc + 512;    // 64
    float* bnsum   = acc + 576;    // 512 (32 ch x 16 stride, padded)
    float* bnsq    = acc + 1088;   // 512 (padded)
    float* cluster = acc + 1600;   // 512
    float* scale   = acc + 2112;   // 32
    float* shift   = acc + 2144;   // 32
    float* epart   = acc + 2176;                          // 8*432 = 3456
    float* dpart   = acc + 2176 + NN*NCC*CHUNKS_PER_N;    // 3456

    hipMemsetAsync(acc, 0, 1600 * sizeof(float), stream);

    k_poolHW    <<<NN*NCC*DD, 256, 0, stream>>>(x, t2, t1);
    k_poolD_dots<<<NN*CHUNKS_PER_N, 512, 0, stream>>>(t2, x, t1, feat,
                                                      dot_e, dot_d, fsum, epart, dpart);
    k_cluster   <<<1, 256, 0, stream>>>(dot_e, dot_d, fsum, epart, dpart, cluster);
    k_attn_stats<<<NN*(PP/1024), 256, 0, stream>>>(feat, cluster, kp, wbuf, bnsum, bnsq);
    k_bnfin     <<<1, 64, 0, stream>>>(bnsum, bnsq, bnw, bnb, scale, shift);
    k_attn_write<<<NN*(PP/1024), 256, 0, stream>>>(feat, cluster, wbuf, kp, scale, shift, out);
}